// Round 12
// baseline (265.203 us; speedup 1.0000x reference)
//
#include <hip/hip_runtime.h>
#include <hip/hip_bf16.h>

#define DEVI __device__ __forceinline__

typedef unsigned short u16;
typedef unsigned int u32;
typedef short short8 __attribute__((ext_vector_type(8)));
typedef float f32x4 __attribute__((ext_vector_type(4)));

#define TT 2048
#define CC 1024
#define NQKV 3072
#define AHAT_B 6291456ll
#define KTD_B 2097152ll
#define VHT_B 3145728ll
#define OBUF_B 2097152ll
#define RI_B 1048576ll
#define GLOG 0.04580368618911996f  /* -log2(gamma) */

DEVI u16 f2bf(float f) {
  union { float f; u32 u; } v; v.f = f;
  u32 u = v.u;
  u32 r = (u + 0x7fffu + ((u >> 16) & 1u)) >> 16;
  return (u16)r;
}

// 4x4 transpose across lane groups {4a..4a+3} (p=lane&3) x regs j.
// In:  lane p, reg j = C[rb+j][cb+p].  Out: lane p, reg j = C[rb+p][cb+j].
DEVI void xpose4(f32x4& v, int lane) {
  const int p = lane & 3;
  f32x4 t;
#pragma unroll
  for (int j = 0; j < 4; ++j) t[j] = __shfl_xor(v[j ^ 1], 1);
#pragma unroll
  for (int j = 0; j < 4; ++j) v[j] = ((j ^ p) & 1) ? t[j] : v[j];
#pragma unroll
  for (int j = 0; j < 4; ++j) t[j] = __shfl_xor(v[j ^ 2], 2);
#pragma unroll
  for (int j = 0; j < 4; ++j) v[j] = ((j ^ p) & 2) ? t[j] : v[j];
}

DEVI void gload16(const u16* g, u16* l) {
  __builtin_amdgcn_global_load_lds(
      (__attribute__((address_space(1))) void*)(u16*)g,
      (__attribute__((address_space(3))) void*)l, 16, 0, 0);
}

// Stage one 128x64 bf16 tile pair (A,B) into LDS buffers: 8 global_load_lds
// per thread (4 A + 4 B). Pre-swizzled global source col (rule 21 + R9-verified
// XOR scheme); LDS dest is linear (wave-uniform base + lane*16).
DEVI void stage_tile64(const u16* __restrict__ A, int lda,
                       const u16* __restrict__ Bt, int ldb,
                       int m0, int n0, int k0, u16* As, u16* Bs,
                       int wv, int srow, int scol)
{
#pragma unroll
  for (int i = 0; i < 4; ++i) {
    const int r = srow + i * 32;
    const int ldsoff = (i * 256 + wv * 64) * 8;     // elems; wave-uniform base
    gload16(A + (size_t)(m0 + r) * lda + (k0 + scol), As + ldsoff);
    gload16(Bt + (size_t)(n0 + r) * ldb + (k0 + scol), Bs + ldsoff);
  }
}

// Compute one staged BK=64 tile: 16 ds_read_b128 + 32 MFMA (R9-verified
// swizzled read: physical col16 = logical ^ (row&7); 2-way conflict = free).
DEVI void compute_tile64(const u16* As, const u16* Bs, f32x4 acc[4][4],
                         int fr, int fq, int wr, int wc, int rsw)
{
#pragma unroll
  for (int h = 0; h < 2; ++h) {
    short8 av[4], bv[4];
    const int coff = ((h * 4 + fq) ^ rsw) * 8;
#pragma unroll
    for (int m = 0; m < 4; ++m)
      av[m] = *(const short8*)(As + (wr * 64 + m * 16 + fr) * 64 + coff);
#pragma unroll
    for (int n = 0; n < 4; ++n)
      bv[n] = *(const short8*)(Bs + (wc * 64 + n * 16 + fr) * 64 + coff);
#pragma unroll
    for (int m = 0; m < 4; ++m)
#pragma unroll
      for (int n = 0; n < 4; ++n)
        acc[m][n] = __builtin_amdgcn_mfma_f32_16x16x32_bf16(av[m], bv[n], acc[m][n], 0, 0, 0);
  }
}

// 128x128 tile, BK=64, 4 waves, 2-deep counted-vmcnt pipeline (T4):
// tile k+1's 8 loads are issued before tile k's compute and stay IN FLIGHT
// across the barrier; each wave waits vmcnt(8) = its tile-k loads only.
// Leading barrier => all waves' tile-k loads landed (each drained its own 8
// before joining). Every ds_read is consumed by MFMA before the trailing
// barrier (compiler lgkm waits), so the trailing barrier protects buf[k]
// against iteration k+1's overwrite. MFMA order identical to the drained
// version => bit-identical accumulation.
DEVI void gemm_kloop(const u16* __restrict__ A, int lda,
                     const u16* __restrict__ Bt, int ldb,
                     int m0, int n0, int kt0, int kt1,
                     u16* As, u16* Bs, f32x4 acc[4][4],
                     int lane, int wv, int wr, int wc)
{
  if (kt0 >= kt1) return;
  const int fr = lane & 15, fq = lane >> 4;
  const int srow = wv * 8 + (lane >> 3);              // staged row (+ i*32)
  const int scol = ((lane & 7) ^ (lane >> 3)) * 8;    // pre-swizzled src col
  const int rsw = fr & 7;                             // read-side XOR
  stage_tile64(A, lda, Bt, ldb, m0, n0, kt0 << 6, As, Bs, wv, srow, scol);
  for (int kt = kt0; kt < kt1; ++kt) {
    const int cur = ((kt - kt0) & 1) << 13;           // 0 or 8192 elems (16KB)
    const int nxt = cur ^ 8192;
    if (kt + 1 < kt1) {
      stage_tile64(A, lda, Bt, ldb, m0, n0, (kt + 1) << 6,
                   As + nxt, Bs + nxt, wv, srow, scol);
      asm volatile("s_waitcnt vmcnt(8)" ::: "memory");   // tile kt landed
    } else {
      asm volatile("s_waitcnt vmcnt(0)" ::: "memory");
    }
    __builtin_amdgcn_s_barrier();
    asm volatile("" ::: "memory");
    compute_tile64(As + cur, Bs + cur, acc, fr, fq, wr, wc, rsw);
    asm volatile("" ::: "memory");
    __builtin_amdgcn_s_barrier();
  }
}

#define GEMM_PROLOG                                        \
  __shared__ alignas(16) u16 As[16384];                    \
  __shared__ alignas(16) u16 Bs[16384];                    \
  const int tid = threadIdx.x;                             \
  const int lane = tid & 63, wv = tid >> 6;                \
  const int wr = wv >> 1, wc = wv & 1;                     \
  const int fr = lane & 15, fq = lane >> 4;                \
  const f32x4 fzero = {0.f, 0.f, 0.f, 0.f};                \
  f32x4 acc[4][4];                                         \
  for (int m = 0; m < 4; ++m)                              \
    for (int n = 0; n < 4; ++n) acc[m][n] = fzero;

// ---------------- prep kernels ----------------

// Fused: X fp32->bf16 (all 2M float4 threads); costab/sintab[t*512+fi]
// (idx < 1M); dpow[i]=gamma^i (idx < 2080).
__global__ __launch_bounds__(256) void k_prep(const float* __restrict__ src,
                                              u16* __restrict__ dst,
                                              float* __restrict__ costab,
                                              float* __restrict__ sintab,
                                              float* __restrict__ dpow)
{
  const int idx = blockIdx.x * 256 + threadIdx.x;   // 8192 blocks -> 2M threads
  const float4 v = *(const float4*)(src + (size_t)idx * 4);
  ushort4 o;
  o.x = f2bf(v.x); o.y = f2bf(v.y); o.z = f2bf(v.z); o.w = f2bf(v.w);
  *(ushort4*)(dst + (size_t)idx * 4) = o;
  if (idx < 2048 * 512) {
    const int t = idx >> 9, fi = idx & 511;
    const float invf = expf(-0.017988946039015984f * (float)fi); // 10000^(-fi/512)
    const float ang = (float)t * invf;
    costab[idx] = cosf(ang);
    sintab[idx] = sinf(ang);
  }
  if (idx < 2080) dpow[idx] = exp2f(-GLOG * (float)idx);
}

// 7 transposes in one launch: z 0..2 -> W matrices (ldd 1024), z 3..6 ->
// Sn batches (ldd 3072, dst offset +2048).
__global__ __launch_bounds__(256) void k_transpose7(
    const float* __restrict__ WQ, const float* __restrict__ WK,
    const float* __restrict__ WV, const float* __restrict__ Sn,
    u16* __restrict__ Wt, u16* __restrict__ VhatT)
{
  const int z = blockIdx.z;
  const float* src;
  u16* dst;
  int ldd;
  if (z == 0)      { src = WQ; dst = Wt;           ldd = 1024; }
  else if (z == 1) { src = WK; dst = Wt + 1048576; ldd = 1024; }
  else if (z == 2) { src = WV; dst = Wt + 2097152; ldd = 1024; }
  else {
    src = Sn + (size_t)(z - 3) * RI_B;
    dst = VhatT + (size_t)(z - 3) * VHT_B + 2048;
    ldd = 3072;
  }
  __shared__ float tile[64][65];
  const int r0 = blockIdx.y * 64, c0 = blockIdx.x * 64;
  const int tid = threadIdx.x;
  const int tr = tid >> 4;
  const int tc = (tid & 15) * 4;
#pragma unroll
  for (int k = 0; k < 4; ++k) {
    const float4 v = *(const float4*)(src + (size_t)(r0 + tr + 16 * k) * 1024 + c0 + tc);
    tile[tr + 16 * k][tc + 0] = v.x;
    tile[tr + 16 * k][tc + 1] = v.y;
    tile[tr + 16 * k][tc + 2] = v.z;
    tile[tr + 16 * k][tc + 3] = v.w;
  }
  __syncthreads();
#pragma unroll
  for (int k = 0; k < 4; ++k) {
    const int n = tr + 16 * k;
    ushort4 o;
    o.x = f2bf(tile[tc + 0][n]);
    o.y = f2bf(tile[tc + 1][n]);
    o.z = f2bf(tile[tc + 2][n]);
    o.w = f2bf(tile[tc + 3][n]);
    *(ushort4*)(dst + (size_t)(c0 + n) * ldd + r0 + tc) = o;
  }
}

// ---------------- GEMM kernels ----------------

// C = Xb(8192x1024) @ Wt^T(3072x1024); R1-shape rope epilogue (shared rope
// path, n-outer/m-inner, scalar table loads). Stores: Qe (Ahat cols 2048+),
// Kd (row-major decayed scalar), Ktd (col-major decayed vec), VhatT (vec).
__global__ __launch_bounds__(256, 4) void k_gemm_qkv(
    const u16* __restrict__ Xb, const u16* __restrict__ Wt,
    u16* __restrict__ Kd, u16* __restrict__ Ktd,
    u16* __restrict__ VhatT, u16* __restrict__ Ahat,
    const float* __restrict__ costab, const float* __restrict__ sintab,
    const float* __restrict__ dpow)
{
  GEMM_PROLOG;
  const int n0 = blockIdx.x * 128, m0 = blockIdx.y * 128;
  gemm_kloop(Xb, CC, Wt, CC, m0, n0, 0, 16, As, Bs, acc, lane, wv, wr, wc);

  const int bb = m0 >> 11;
  const int tb0 = m0 & 2047;

#pragma unroll
  for (int n = 0; n < 4; ++n) {
    const int col = n0 + wc * 64 + n * 16 + fr;
#pragma unroll
    for (int m = 0; m < 4; ++m) {
      const int tl = tb0 + wr * 64 + m * 16 + fq * 4;
      f32x4 v = acc[m][n];
      if (col < 2048) {
        const int c = col & 1023;
        const int fi = c >> 1;
        const float sg = (col & 1) ? 1.0f : -1.0f;
        float y[4];
#pragma unroll
        for (int j = 0; j < 4; ++j) {
          const float other = __shfl_xor(v[j], 1);
          const float cs = costab[(size_t)(tl + j) * 512 + fi];
          const float sn = sintab[(size_t)(tl + j) * 512 + fi];
          y[j] = v[j] * cs + sg * other * sn;
        }
        if (col < 1024) {
          // Qe = rope(Q) * gamma^(t+1), scalar coalesced into Ahat
#pragma unroll
          for (int j = 0; j < 4; ++j)
            Ahat[bb * AHAT_B + (size_t)(tl + j) * NQKV + 2048 + c] =
                f2bf(y[j] * dpow[tl + j + 1]);
        } else {
          // K * gamma^(2047-t): pack once -> Ktd vec + Kd scalar
          ushort4 pk;
          u16* pkp = (u16*)&pk;
#pragma unroll
          for (int j = 0; j < 4; ++j)
            pkp[j] = f2bf(y[j] * dpow[2047 - tl - j]);
          *(ushort4*)(Ktd + bb * KTD_B + (size_t)c * TT + tl) = pk;
#pragma unroll
          for (int j = 0; j < 4; ++j)
            Kd[bb * KTD_B + (size_t)(tl + j) * CC + c] = pkp[j];
        }
      } else {
        const int o = col - 2048;
        ushort4 pk;
        pk.x = f2bf(v[0]); pk.y = f2bf(v[1]); pk.z = f2bf(v[2]); pk.w = f2bf(v[3]);
        *(ushort4*)(VhatT + bb * VHT_B + (size_t)o * NQKV + tl) = pk;
      }
    }
  }
}

// Fused independent mid-stage GEMMs (both consume only qkv outputs):
//  x < 136: A[t][s] = (Qe Kd^T)*gamma^-2048, masked s<=t (lower-tri tiles)
//  x >= 136: R_i = Ktd @ V^T + gamma^T*S_n (64 tiles)
__global__ __launch_bounds__(256, 4) void k_gemm_ari(
    const u16* __restrict__ Ahat_ro, const u16* __restrict__ Kd,
    u16* __restrict__ Ahat,
    const u16* __restrict__ Ktd, const u16* __restrict__ VhatT,
    const float* __restrict__ Sn, float* __restrict__ out1,
    const float* __restrict__ dpow)
{
  GEMM_PROLOG;
  const int b = blockIdx.z;
  if (blockIdx.x < 136) {
    const int lin = blockIdx.x;          // 0..135
    int mi = 0;
    while ((mi + 1) * (mi + 2) / 2 <= lin) ++mi;   // largest mi: T(mi) <= lin
    const int ni = lin - mi * (mi + 1) / 2;        // 0 <= ni <= mi
    const int m0 = mi * 128, n0 = ni * 128;
    gemm_kloop(Ahat_ro + b * AHAT_B + 2048, NQKV, Kd + b * KTD_B, CC,
               m0, n0, 0, 16, As, Bs, acc, lane, wv, wr, wc);
    const float invC = exp2f(GLOG * 2048.0f);  // gamma^-2048
    u16* Ab = Ahat + b * AHAT_B;
#pragma unroll
    for (int m = 0; m < 4; ++m) {
      const int t = m0 + wr * 64 + m * 16 + fq * 4 + (fr & 3);
#pragma unroll
      for (int n = 0; n < 4; ++n) {
        const int s0 = n0 + wc * 64 + n * 16 + (fr >> 2) * 4;
        f32x4 v = acc[m][n];
        xpose4(v, lane);
        ushort4 pk;
        pk.x = f2bf(s0 + 0 <= t ? v[0] * invC : 0.f);
        pk.y = f2bf(s0 + 1 <= t ? v[1] * invC : 0.f);
        pk.z = f2bf(s0 + 2 <= t ? v[2] * invC : 0.f);
        pk.w = f2bf(s0 + 3 <= t ? v[3] * invC : 0.f);
        *(ushort4*)(Ab + (size_t)t * NQKV + s0) = pk;
      }
    }
  } else {
    const int lin = blockIdx.x - 136;    // 0..63
    const int n0 = (lin & 7) * 128;
    const int m0 = (lin >> 3) * 128;
    gemm_kloop(Ktd + b * KTD_B, TT, VhatT + b * VHT_B, NQKV,
               m0, n0, 0, 32, As, Bs, acc, lane, wv, wr, wc);
    const float gT = dpow[2048];
    const float* Sb = Sn + b * RI_B;
    float* Rb = out1 + b * RI_B;
#pragma unroll
    for (int m = 0; m < 4; ++m) {
      const int c = m0 + wr * 64 + m * 16 + fq * 4 + (fr & 3);
#pragma unroll
      for (int n = 0; n < 4; ++n) {
        const int o0 = n0 + wc * 64 + n * 16 + (fr >> 2) * 4;
        f32x4 v = acc[m][n];
        xpose4(v, lane);
        const float4 s4 = *(const float4*)(Sb + (size_t)c * CC + o0);
        v[0] += gT * s4.x; v[1] += gT * s4.y;
        v[2] += gT * s4.z; v[3] += gT * s4.w;
        *(f32x4*)(Rb + (size_t)c * CC + o0) = v;
      }
    }
  }
}

// out = Ahat(2048x3072) @ VhatT^T -> fp32 Obuf[t][o]
__global__ __launch_bounds__(256, 4) void k_gemm_out(
    const u16* __restrict__ Ahat, const u16* __restrict__ VhatT,
    float* __restrict__ Obuf)
{
  GEMM_PROLOG;
  const int n0 = blockIdx.x * 128;
  const int m0 = blockIdx.y * 128;
  const int b = blockIdx.z;
  const u16* A = Ahat + b * AHAT_B;
  const u16* Bt = VhatT + b * VHT_B;
  const int kt1 = (m0 >> 6) + 2;   // only s <= t_max tiles are nonzero (BK=64)
  gemm_kloop(A, NQKV, Bt, NQKV, m0, n0, 0, kt1, As, Bs, acc, lane, wv, wr, wc);
  gemm_kloop(A, NQKV, Bt, NQKV, m0, n0, 32, 48, As, Bs, acc, lane, wv, wr, wc);
  float* Ob = Obuf + b * OBUF_B;
#pragma unroll
  for (int m = 0; m < 4; ++m) {
    const int t = m0 + wr * 64 + m * 16 + fq * 4 + (fr & 3);
    float* orow = Ob + (size_t)t * CC;
#pragma unroll
    for (int n = 0; n < 4; ++n) {
      const int c0 = n0 + wc * 64 + n * 16 + (fr >> 2) * 4;
      f32x4 v = acc[m][n];
      xpose4(v, lane);
      *(f32x4*)(orow + c0) = v;
    }
  }
}

// ---------------- GroupNorm + transposed output ----------------
// 16 t-rows per block (64 KB LDS) -> 2 blocks/CU for a memory-bound kernel.
__global__ __launch_bounds__(256) void k_gn(
    const float* __restrict__ Obuf, const float* __restrict__ gw,
    const float* __restrict__ gb, float* __restrict__ out)
{
  __shared__ float L[16][1024];
  const int bi = blockIdx.x;
  const int b = bi >> 7;
  const int t0 = (bi & 127) << 4;
  const int tid = threadIdx.x;
  const int lane = tid & 63, wv = tid >> 6;
  float wgt[16], bsv[16];
#pragma unroll
  for (int k = 0; k < 4; ++k) {
    const float4 w4 = *(const float4*)(gw + k * 256 + lane * 4);
    const float4 b4 = *(const float4*)(gb + k * 256 + lane * 4);
    wgt[k*4+0]=w4.x; wgt[k*4+1]=w4.y; wgt[k*4+2]=w4.z; wgt[k*4+3]=w4.w;
    bsv[k*4+0]=b4.x; bsv[k*4+1]=b4.y; bsv[k*4+2]=b4.z; bsv[k*4+3]=b4.w;
  }
  for (int r = wv; r < 16; r += 4) {
    const float* src = Obuf + (size_t)(b * 2048 + t0 + r) * 1024;
#pragma unroll
    for (int k = 0; k < 4; ++k) {
      const float4 x = *(const float4*)(src + k * 256 + lane * 4);
      float s = x.x + x.y + x.z + x.w;
      float q = x.x*x.x + x.y*x.y + x.z*x.z + x.w*x.w;
      s += __shfl_xor(s, 1); q += __shfl_xor(q, 1);
      s += __shfl_xor(s, 2); q += __shfl_xor(q, 2);
      s += __shfl_xor(s, 4); q += __shfl_xor(q, 4);
      const float mu = s * 0.03125f;
      const float var = q * 0.03125f - mu * mu;
      const float rs = rsqrtf(var + 1e-6f);
      float4 y;
      y.x = (x.x - mu) * rs * wgt[k*4+0] + bsv[k*4+0];
      y.y = (x.y - mu) * rs * wgt[k*4+1] + bsv[k*4+1];
      y.z = (x.z - mu) * rs * wgt[k*4+2] + bsv[k*4+2];
      y.w = (x.w - mu) * rs * wgt[k*4+3] + bsv[k*4+3];
      *(float4*)&L[r][k * 256 + lane * 4] = y;
    }
  }
  __syncthreads();
  const size_t obase = (size_t)b * 2097152 + t0;
  for (int c = tid; c < 1024; c += 256) {
    float* dst = out + obase + (size_t)c * 2048;
#pragma unroll
    for (int i = 0; i < 4; ++i) {
      float4 o4;
      o4.x = L[i*4+0][c]; o4.y = L[i*4+1][c]; o4.z = L[i*4+2][c]; o4.w = L[i*4+3][c];
      *(float4*)(dst + i * 4) = o4;
    }
  }
}

// ---------------- launch ----------------

extern "C" void kernel_launch(void* const* d_in, const int* in_sizes, int n_in,
                              void* d_out, int out_size, void* d_ws, size_t ws_size,
                              hipStream_t stream)
{
  const float* XQ = (const float*)d_in[0];
  const float* Sn = (const float*)d_in[1];
  const float* WQ = (const float*)d_in[2];
  const float* WK = (const float*)d_in[3];
  const float* WV = (const float*)d_in[4];
  const float* gw = (const float*)d_in[5];
  const float* gb = (const float*)d_in[6];
  float* out0 = (float*)d_out;
  float* out1 = out0 + 8388608;

  char* ws = (char*)d_ws;
  u16* Xb      = (u16*)(ws);                   // 16 MB (dead after qkv)
  u16* Kd      = (u16*)(ws + (16ll << 20));    // 16 MB (dead after gemm_ari)
  u16* Ktd     = (u16*)(ws + (32ll << 20));    // 16 MB
  u16* Ahat    = (u16*)(ws + (48ll << 20));    // 48 MB [t][0:2048]=A, [2048:3072]=Qe
  u16* VhatT   = (u16*)(ws + (96ll << 20));    // 24 MB [o][0:2048]=V^T, [2048:3072]=Sn^T
  u16* Wt      = (u16*)(ws + (120ll << 20));   // 6 MB
  float* costab = (float*)(ws + (126ll << 20)); // 4 MB
  float* sintab = (float*)(ws + (130ll << 20)); // 4 MB
  float* dpow   = (float*)(ws + (134ll << 20)); // ~8 KB
  float* Obuf   = (float*)(ws);                // 32 MB, aliases Xb+Kd (both dead)

  k_prep<<<8192, 256, 0, stream>>>(XQ, Xb, costab, sintab, dpow);
  k_transpose7<<<dim3(16, 16, 7), 256, 0, stream>>>(WQ, WK, WV, Sn, Wt, VhatT);
  k_gemm_qkv<<<dim3(24, 64), 256, 0, stream>>>(Xb, Wt, Kd, Ktd, VhatT, Ahat,
                                               costab, sintab, dpow);
  k_gemm_ari<<<dim3(200, 1, 4), 256, 0, stream>>>(Ahat, Kd, Ahat, Ktd, VhatT,
                                                  Sn, out1, dpow);
  k_gemm_out<<<dim3(8, 16, 4), 256, 0, stream>>>(Ahat, VhatT, Obuf);
  k_gn<<<512, 256, 0, stream>>>(Obuf, gw, gb, out0);
}

// Round 13
// 249.977 us; speedup vs baseline: 1.0609x; 1.0609x over previous
//
#include <hip/hip_runtime.h>
#include <hip/hip_bf16.h>

#define DEVI __device__ __forceinline__

typedef unsigned short u16;
typedef unsigned int u32;
typedef short short8 __attribute__((ext_vector_type(8)));
typedef float f32x4 __attribute__((ext_vector_type(4)));

#define TT 2048
#define CC 1024
#define NQKV 3072
#define AHAT_B 6291456ll
#define KTD_B 2097152ll
#define VHT_B 3145728ll
#define OBUF_B 2097152ll
#define RI_B 1048576ll
#define GLOG 0.04580368618911996f  /* -log2(gamma) */

DEVI u16 f2bf(float f) {
  union { float f; u32 u; } v; v.f = f;
  u32 u = v.u;
  u32 r = (u + 0x7fffu + ((u >> 16) & 1u)) >> 16;
  return (u16)r;
}

// 4x4 transpose across lane groups {4a..4a+3} (p=lane&3) x regs j.
// In:  lane p, reg j = C[rb+j][cb+p].  Out: lane p, reg j = C[rb+p][cb+j].
DEVI void xpose4(f32x4& v, int lane) {
  const int p = lane & 3;
  f32x4 t;
#pragma unroll
  for (int j = 0; j < 4; ++j) t[j] = __shfl_xor(v[j ^ 1], 1);
#pragma unroll
  for (int j = 0; j < 4; ++j) v[j] = ((j ^ p) & 1) ? t[j] : v[j];
#pragma unroll
  for (int j = 0; j < 4; ++j) t[j] = __shfl_xor(v[j ^ 2], 2);
#pragma unroll
  for (int j = 0; j < 4; ++j) v[j] = ((j ^ p) & 2) ? t[j] : v[j];
}

DEVI void gload16(const u16* g, u16* l) {
  __builtin_amdgcn_global_load_lds(
      (__attribute__((address_space(1))) void*)(u16*)g,
      (__attribute__((address_space(3))) void*)l, 16, 0, 0);
}

// 128x128 tile, BK=64, 4 waves (2x2 of 64x64), 2-barrier per step (m97 sync
// skeleton — R11-proven; R12's counted-vmcnt dbuf regressed via occupancy).
// LDS rows are 128B -> XOR swizzle (T2) applied legally with global_load_lds
// (rule 21): linear LDS dest + pre-swizzled GLOBAL source + swizzled ds_read.
DEVI void gemm_kloop(const u16* __restrict__ A, int lda,
                     const u16* __restrict__ Bt, int ldb,
                     int m0, int n0, int kt0, int kt1,
                     u16* As, u16* Bs, f32x4 acc[4][4],
                     int lane, int wv, int wr, int wc)
{
  const int fr = lane & 15, fq = lane >> 4;
  const int srow = wv * 8 + (lane >> 3);              // staged row (+ i*32)
  const int scol = ((lane & 7) ^ (lane >> 3)) * 8;    // pre-swizzled src col
  const int rsw = fr & 7;                             // read-side XOR
  for (int kt = kt0; kt < kt1; ++kt) {
    const int k0 = kt << 6;
#pragma unroll
    for (int i = 0; i < 4; ++i) {
      const int r = srow + i * 32;
      const int ldsoff = (i * 256 + wv * 64) * 8;     // elems; wave-uniform base
      gload16(A + (size_t)(m0 + r) * lda + (k0 + scol), As + ldsoff);
      gload16(Bt + (size_t)(n0 + r) * ldb + (k0 + scol), Bs + ldsoff);
    }
    __syncthreads();
#pragma unroll
    for (int h = 0; h < 2; ++h) {
      short8 av[4], bv[4];
      const int coff = ((h * 4 + fq) ^ rsw) * 8;
#pragma unroll
      for (int m = 0; m < 4; ++m)
        av[m] = *(const short8*)(As + (wr * 64 + m * 16 + fr) * 64 + coff);
#pragma unroll
      for (int n = 0; n < 4; ++n)
        bv[n] = *(const short8*)(Bs + (wc * 64 + n * 16 + fr) * 64 + coff);
#pragma unroll
      for (int m = 0; m < 4; ++m)
#pragma unroll
        for (int n = 0; n < 4; ++n)
          acc[m][n] = __builtin_amdgcn_mfma_f32_16x16x32_bf16(av[m], bv[n], acc[m][n], 0, 0, 0);
    }
    __syncthreads();
  }
}

#define GEMM_PROLOG                                        \
  __shared__ alignas(16) u16 As[8192];                     \
  __shared__ alignas(16) u16 Bs[8192];                     \
  const int tid = threadIdx.x;                             \
  const int lane = tid & 63, wv = tid >> 6;                \
  const int wr = wv >> 1, wc = wv & 1;                     \
  const int fr = lane & 15, fq = lane >> 4;                \
  const f32x4 fzero = {0.f, 0.f, 0.f, 0.f};                \
  f32x4 acc[4][4];                                         \
  for (int m = 0; m < 4; ++m)                              \
    for (int n = 0; n < 4; ++n) acc[m][n] = fzero;

// ---------------- prep kernels ----------------

// Fused: X fp32->bf16 (all 2M float4 threads); costab/sintab[t*512+fi]
// (idx < 1M); dpow[i]=gamma^i (idx < 2080).
__global__ __launch_bounds__(256) void k_prep(const float* __restrict__ src,
                                              u16* __restrict__ dst,
                                              float* __restrict__ costab,
                                              float* __restrict__ sintab,
                                              float* __restrict__ dpow)
{
  const int idx = blockIdx.x * 256 + threadIdx.x;   // 8192 blocks -> 2M threads
  const float4 v = *(const float4*)(src + (size_t)idx * 4);
  ushort4 o;
  o.x = f2bf(v.x); o.y = f2bf(v.y); o.z = f2bf(v.z); o.w = f2bf(v.w);
  *(ushort4*)(dst + (size_t)idx * 4) = o;
  if (idx < 2048 * 512) {
    const int t = idx >> 9, fi = idx & 511;
    const float invf = expf(-0.017988946039015984f * (float)fi); // 10000^(-fi/512)
    const float ang = (float)t * invf;
    costab[idx] = cosf(ang);
    sintab[idx] = sinf(ang);
  }
  if (idx < 2080) dpow[idx] = exp2f(-GLOG * (float)idx);
}

// 7 transposes in one launch: z 0..2 -> W matrices (ldd 1024), z 3..6 ->
// Sn batches (ldd 3072, dst offset +2048).
__global__ __launch_bounds__(256) void k_transpose7(
    const float* __restrict__ WQ, const float* __restrict__ WK,
    const float* __restrict__ WV, const float* __restrict__ Sn,
    u16* __restrict__ Wt, u16* __restrict__ VhatT)
{
  const int z = blockIdx.z;
  const float* src;
  u16* dst;
  int ldd;
  if (z == 0)      { src = WQ; dst = Wt;           ldd = 1024; }
  else if (z == 1) { src = WK; dst = Wt + 1048576; ldd = 1024; }
  else if (z == 2) { src = WV; dst = Wt + 2097152; ldd = 1024; }
  else {
    src = Sn + (size_t)(z - 3) * RI_B;
    dst = VhatT + (size_t)(z - 3) * VHT_B + 2048;
    ldd = 3072;
  }
  __shared__ float tile[64][65];
  const int r0 = blockIdx.y * 64, c0 = blockIdx.x * 64;
  const int tid = threadIdx.x;
  const int tr = tid >> 4;
  const int tc = (tid & 15) * 4;
#pragma unroll
  for (int k = 0; k < 4; ++k) {
    const float4 v = *(const float4*)(src + (size_t)(r0 + tr + 16 * k) * 1024 + c0 + tc);
    tile[tr + 16 * k][tc + 0] = v.x;
    tile[tr + 16 * k][tc + 1] = v.y;
    tile[tr + 16 * k][tc + 2] = v.z;
    tile[tr + 16 * k][tc + 3] = v.w;
  }
  __syncthreads();
#pragma unroll
  for (int k = 0; k < 4; ++k) {
    const int n = tr + 16 * k;
    ushort4 o;
    o.x = f2bf(tile[tc + 0][n]);
    o.y = f2bf(tile[tc + 1][n]);
    o.z = f2bf(tile[tc + 2][n]);
    o.w = f2bf(tile[tc + 3][n]);
    *(ushort4*)(dst + (size_t)(c0 + n) * ldd + r0 + tc) = o;
  }
}

// ---------------- GEMM kernels ----------------

// C = Xb(8192x1024) @ Wt^T(3072x1024); R1-shape rope epilogue (shared rope
// path, n-outer/m-inner, scalar table loads). Stores: Qe (Ahat cols 2048+),
// Kd (row-major decayed scalar), Ktd (col-major decayed vec), VhatT (vec).
__global__ __launch_bounds__(256, 4) void k_gemm_qkv(
    const u16* __restrict__ Xb, const u16* __restrict__ Wt,
    u16* __restrict__ Kd, u16* __restrict__ Ktd,
    u16* __restrict__ VhatT, u16* __restrict__ Ahat,
    const float* __restrict__ costab, const float* __restrict__ sintab,
    const float* __restrict__ dpow)
{
  GEMM_PROLOG;
  const int n0 = blockIdx.x * 128, m0 = blockIdx.y * 128;
  gemm_kloop(Xb, CC, Wt, CC, m0, n0, 0, 16, As, Bs, acc, lane, wv, wr, wc);

  const int bb = m0 >> 11;
  const int tb0 = m0 & 2047;

#pragma unroll
  for (int n = 0; n < 4; ++n) {
    const int col = n0 + wc * 64 + n * 16 + fr;
#pragma unroll
    for (int m = 0; m < 4; ++m) {
      const int tl = tb0 + wr * 64 + m * 16 + fq * 4;
      f32x4 v = acc[m][n];
      if (col < 2048) {
        const int c = col & 1023;
        const int fi = c >> 1;
        const float sg = (col & 1) ? 1.0f : -1.0f;
        float y[4];
#pragma unroll
        for (int j = 0; j < 4; ++j) {
          const float other = __shfl_xor(v[j], 1);
          const float cs = costab[(size_t)(tl + j) * 512 + fi];
          const float sn = sintab[(size_t)(tl + j) * 512 + fi];
          y[j] = v[j] * cs + sg * other * sn;
        }
        if (col < 1024) {
          // Qe = rope(Q) * gamma^(t+1), scalar coalesced into Ahat
#pragma unroll
          for (int j = 0; j < 4; ++j)
            Ahat[bb * AHAT_B + (size_t)(tl + j) * NQKV + 2048 + c] =
                f2bf(y[j] * dpow[tl + j + 1]);
        } else {
          // K * gamma^(2047-t): pack once -> Ktd vec + Kd scalar
          ushort4 pk;
          u16* pkp = (u16*)&pk;
#pragma unroll
          for (int j = 0; j < 4; ++j)
            pkp[j] = f2bf(y[j] * dpow[2047 - tl - j]);
          *(ushort4*)(Ktd + bb * KTD_B + (size_t)c * TT + tl) = pk;
#pragma unroll
          for (int j = 0; j < 4; ++j)
            Kd[bb * KTD_B + (size_t)(tl + j) * CC + c] = pkp[j];
        }
      } else {
        const int o = col - 2048;
        ushort4 pk;
        pk.x = f2bf(v[0]); pk.y = f2bf(v[1]); pk.z = f2bf(v[2]); pk.w = f2bf(v[3]);
        *(ushort4*)(VhatT + bb * VHT_B + (size_t)o * NQKV + tl) = pk;
      }
    }
  }
}

// Fused independent mid-stage GEMMs (both consume only qkv outputs):
//  x < 64:  R_i = Ktd @ V^T + gamma^T*S_n (32 K-tiles each — HEAVY, first so
//           the 800-block straggler round is light a-blocks)
//  x >= 64: A[t][s] = (Qe Kd^T)*gamma^-2048, masked s<=t (16 K-tiles each)
__global__ __launch_bounds__(256, 4) void k_gemm_ari(
    const u16* __restrict__ Ahat_ro, const u16* __restrict__ Kd,
    u16* __restrict__ Ahat,
    const u16* __restrict__ Ktd, const u16* __restrict__ VhatT,
    const float* __restrict__ Sn, float* __restrict__ out1,
    const float* __restrict__ dpow)
{
  GEMM_PROLOG;
  const int b = blockIdx.z;
  if (blockIdx.x < 64) {
    const int lin = blockIdx.x;          // 0..63
    const int n0 = (lin & 7) * 128;
    const int m0 = (lin >> 3) * 128;
    gemm_kloop(Ktd + b * KTD_B, TT, VhatT + b * VHT_B, NQKV,
               m0, n0, 0, 32, As, Bs, acc, lane, wv, wr, wc);
    const float gT = dpow[2048];
    const float* Sb = Sn + b * RI_B;
    float* Rb = out1 + b * RI_B;
#pragma unroll
    for (int m = 0; m < 4; ++m) {
      const int c = m0 + wr * 64 + m * 16 + fq * 4 + (fr & 3);
#pragma unroll
      for (int n = 0; n < 4; ++n) {
        const int o0 = n0 + wc * 64 + n * 16 + (fr >> 2) * 4;
        f32x4 v = acc[m][n];
        xpose4(v, lane);
        const float4 s4 = *(const float4*)(Sb + (size_t)c * CC + o0);
        v[0] += gT * s4.x; v[1] += gT * s4.y;
        v[2] += gT * s4.z; v[3] += gT * s4.w;
        *(f32x4*)(Rb + (size_t)c * CC + o0) = v;
      }
    }
  } else {
    const int lin = blockIdx.x - 64;     // 0..135
    int mi = 0;
    while ((mi + 1) * (mi + 2) / 2 <= lin) ++mi;   // largest mi: T(mi) <= lin
    const int ni = lin - mi * (mi + 1) / 2;        // 0 <= ni <= mi
    const int m0 = mi * 128, n0 = ni * 128;
    gemm_kloop(Ahat_ro + b * AHAT_B + 2048, NQKV, Kd + b * KTD_B, CC,
               m0, n0, 0, 16, As, Bs, acc, lane, wv, wr, wc);
    const float invC = exp2f(GLOG * 2048.0f);  // gamma^-2048
    u16* Ab = Ahat + b * AHAT_B;
#pragma unroll
    for (int m = 0; m < 4; ++m) {
      const int t = m0 + wr * 64 + m * 16 + fq * 4 + (fr & 3);
#pragma unroll
      for (int n = 0; n < 4; ++n) {
        const int s0 = n0 + wc * 64 + n * 16 + (fr >> 2) * 4;
        f32x4 v = acc[m][n];
        xpose4(v, lane);
        ushort4 pk;
        pk.x = f2bf(s0 + 0 <= t ? v[0] * invC : 0.f);
        pk.y = f2bf(s0 + 1 <= t ? v[1] * invC : 0.f);
        pk.z = f2bf(s0 + 2 <= t ? v[2] * invC : 0.f);
        pk.w = f2bf(s0 + 3 <= t ? v[3] * invC : 0.f);
        *(ushort4*)(Ab + (size_t)t * NQKV + s0) = pk;
      }
    }
  }
}

// out = Ahat(2048x3072) @ VhatT^T -> fp32 Obuf[t][o]
// Per-block K-work = 2*mi+18 tiles. Blocks i and i+256 share a CU under
// sequential fill and differ only in z -> same mi -> CU loads 36..96 tiles.
// Fix: flip mi for z>=2 so each CU pairs mi with 15-mi -> constant 66 tiles.
__global__ __launch_bounds__(256, 4) void k_gemm_out(
    const u16* __restrict__ Ahat, const u16* __restrict__ VhatT,
    float* __restrict__ Obuf)
{
  GEMM_PROLOG;
  const int n0 = blockIdx.x * 128;
  int mi = blockIdx.y;
  if (blockIdx.z >= 2) mi = 15 - mi;     // load-balance pairing (no math change)
  const int m0 = mi * 128;
  const int b = blockIdx.z;
  const u16* A = Ahat + b * AHAT_B;
  const u16* Bt = VhatT + b * VHT_B;
  const int kt1 = (m0 >> 6) + 2;   // only s <= t_max tiles are nonzero (BK=64)
  gemm_kloop(A, NQKV, Bt, NQKV, m0, n0, 0, kt1, As, Bs, acc, lane, wv, wr, wc);
  gemm_kloop(A, NQKV, Bt, NQKV, m0, n0, 32, 48, As, Bs, acc, lane, wv, wr, wc);
  float* Ob = Obuf + b * OBUF_B;
#pragma unroll
  for (int m = 0; m < 4; ++m) {
    const int t = m0 + wr * 64 + m * 16 + fq * 4 + (fr & 3);
    float* orow = Ob + (size_t)t * CC;
#pragma unroll
    for (int n = 0; n < 4; ++n) {
      const int c0 = n0 + wc * 64 + n * 16 + (fr >> 2) * 4;
      f32x4 v = acc[m][n];
      xpose4(v, lane);
      *(f32x4*)(orow + c0) = v;
    }
  }
}

// ---------------- GroupNorm + transposed output ----------------
// 16 t-rows per block (64 KB LDS) -> 2 blocks/CU for a memory-bound kernel.
__global__ __launch_bounds__(256) void k_gn(
    const float* __restrict__ Obuf, const float* __restrict__ gw,
    const float* __restrict__ gb, float* __restrict__ out)
{
  __shared__ float L[16][1024];
  const int bi = blockIdx.x;
  const int b = bi >> 7;
  const int t0 = (bi & 127) << 4;
  const int tid = threadIdx.x;
  const int lane = tid & 63, wv = tid >> 6;
  float wgt[16], bsv[16];
#pragma unroll
  for (int k = 0; k < 4; ++k) {
    const float4 w4 = *(const float4*)(gw + k * 256 + lane * 4);
    const float4 b4 = *(const float4*)(gb + k * 256 + lane * 4);
    wgt[k*4+0]=w4.x; wgt[k*4+1]=w4.y; wgt[k*4+2]=w4.z; wgt[k*4+3]=w4.w;
    bsv[k*4+0]=b4.x; bsv[k*4+1]=b4.y; bsv[k*4+2]=b4.z; bsv[k*4+3]=b4.w;
  }
  for (int r = wv; r < 16; r += 4) {
    const float* src = Obuf + (size_t)(b * 2048 + t0 + r) * 1024;
#pragma unroll
    for (int k = 0; k < 4; ++k) {
      const float4 x = *(const float4*)(src + k * 256 + lane * 4);
      float s = x.x + x.y + x.z + x.w;
      float q = x.x*x.x + x.y*x.y + x.z*x.z + x.w*x.w;
      s += __shfl_xor(s, 1); q += __shfl_xor(q, 1);
      s += __shfl_xor(s, 2); q += __shfl_xor(q, 2);
      s += __shfl_xor(s, 4); q += __shfl_xor(q, 4);
      const float mu = s * 0.03125f;
      const float var = q * 0.03125f - mu * mu;
      const float rs = rsqrtf(var + 1e-6f);
      float4 y;
      y.x = (x.x - mu) * rs * wgt[k*4+0] + bsv[k*4+0];
      y.y = (x.y - mu) * rs * wgt[k*4+1] + bsv[k*4+1];
      y.z = (x.z - mu) * rs * wgt[k*4+2] + bsv[k*4+2];
      y.w = (x.w - mu) * rs * wgt[k*4+3] + bsv[k*4+3];
      *(float4*)&L[r][k * 256 + lane * 4] = y;
    }
  }
  __syncthreads();
  const size_t obase = (size_t)b * 2097152 + t0;
  for (int c = tid; c < 1024; c += 256) {
    float* dst = out + obase + (size_t)c * 2048;
#pragma unroll
    for (int i = 0; i < 4; ++i) {
      float4 o4;
      o4.x = L[i*4+0][c]; o4.y = L[i*4+1][c]; o4.z = L[i*4+2][c]; o4.w = L[i*4+3][c];
      *(float4*)(dst + i * 4) = o4;
    }
  }
}

// ---------------- launch ----------------

extern "C" void kernel_launch(void* const* d_in, const int* in_sizes, int n_in,
                              void* d_out, int out_size, void* d_ws, size_t ws_size,
                              hipStream_t stream)
{
  const float* XQ = (const float*)d_in[0];
  const float* Sn = (const float*)d_in[1];
  const float* WQ = (const float*)d_in[2];
  const float* WK = (const float*)d_in[3];
  const float* WV = (const float*)d_in[4];
  const float* gw = (const float*)d_in[5];
  const float* gb = (const float*)d_in[6];
  float* out0 = (float*)d_out;
  float* out1 = out0 + 8388608;

  char* ws = (char*)d_ws;
  u16* Xb      = (u16*)(ws);                   // 16 MB (dead after qkv)
  u16* Kd      = (u16*)(ws + (16ll << 20));    // 16 MB (dead after gemm_ari)
  u16* Ktd     = (u16*)(ws + (32ll << 20));    // 16 MB
  u16* Ahat    = (u16*)(ws + (48ll << 20));    // 48 MB [t][0:2048]=A, [2048:3072]=Qe
  u16* VhatT   = (u16*)(ws + (96ll << 20));    // 24 MB [o][0:2048]=V^T, [2048:3072]=Sn^T
  u16* Wt      = (u16*)(ws + (120ll << 20));   // 6 MB
  float* costab = (float*)(ws + (126ll << 20)); // 4 MB
  float* sintab = (float*)(ws + (130ll << 20)); // 4 MB
  float* dpow   = (float*)(ws + (134ll << 20)); // ~8 KB
  float* Obuf   = (float*)(ws);                // 32 MB, aliases Xb+Kd (both dead)

  k_prep<<<8192, 256, 0, stream>>>(XQ, Xb, costab, sintab, dpow);
  k_transpose7<<<dim3(16, 16, 7), 256, 0, stream>>>(WQ, WK, WV, Sn, Wt, VhatT);
  k_gemm_qkv<<<dim3(24, 64), 256, 0, stream>>>(Xb, Wt, Kd, Ktd, VhatT, Ahat,
                                               costab, sintab, dpow);
  k_gemm_ari<<<dim3(200, 1, 4), 256, 0, stream>>>(Ahat, Kd, Ahat, Ktd, VhatT,
                                                  Sn, out1, dpow);
  k_gemm_out<<<dim3(8, 16, 4), 256, 0, stream>>>(Ahat, VhatT, Obuf);
  k_gn<<<512, 256, 0, stream>>>(Obuf, gw, gb, out0);
}

// Round 15
// 248.296 us; speedup vs baseline: 1.0681x; 1.0068x over previous
//
#include <hip/hip_runtime.h>
#include <hip/hip_bf16.h>

#define DEVI __device__ __forceinline__

typedef unsigned short u16;
typedef unsigned int u32;
typedef short short8 __attribute__((ext_vector_type(8)));
typedef float f32x4 __attribute__((ext_vector_type(4)));

#define TT 2048
#define CC 1024
#define NQKV 3072
#define AHAT_B 6291456ll
#define KTD_B 2097152ll
#define VHT_B 3145728ll
#define OBUF_B 2097152ll
#define RI_B 1048576ll
#define GLOG 0.04580368618911996f  /* -log2(gamma) */

DEVI u16 f2bf(float f) {
  union { float f; u32 u; } v; v.f = f;
  u32 u = v.u;
  u32 r = (u + 0x7fffu + ((u >> 16) & 1u)) >> 16;
  return (u16)r;
}

// 4x4 transpose across lane groups {4a..4a+3} (p=lane&3) x regs j.
// In:  lane p, reg j = C[rb+j][cb+p].  Out: lane p, reg j = C[rb+p][cb+j].
DEVI void xpose4(f32x4& v, int lane) {
  const int p = lane & 3;
  f32x4 t;
#pragma unroll
  for (int j = 0; j < 4; ++j) t[j] = __shfl_xor(v[j ^ 1], 1);
#pragma unroll
  for (int j = 0; j < 4; ++j) v[j] = ((j ^ p) & 1) ? t[j] : v[j];
#pragma unroll
  for (int j = 0; j < 4; ++j) t[j] = __shfl_xor(v[j ^ 2], 2);
#pragma unroll
  for (int j = 0; j < 4; ++j) v[j] = ((j ^ p) & 2) ? t[j] : v[j];
}

DEVI void gload16(const u16* g, u16* l) {
  __builtin_amdgcn_global_load_lds(
      (__attribute__((address_space(1))) void*)(u16*)g,
      (__attribute__((address_space(3))) void*)l, 16, 0, 0);
}

// 128x128 tile, BK=64, 4 waves (2x2 of 64x64), 2-barrier per step (m97 sync
// skeleton — R11-proven). LDS rows are 128B -> XOR swizzle (T2) applied
// legally with global_load_lds (rule 21): linear LDS dest + pre-swizzled
// GLOBAL source + swizzled ds_read.
DEVI void gemm_kloop(const u16* __restrict__ A, int lda,
                     const u16* __restrict__ Bt, int ldb,
                     int m0, int n0, int kt0, int kt1,
                     u16* As, u16* Bs, f32x4 acc[4][4],
                     int lane, int wv, int wr, int wc)
{
  const int fr = lane & 15, fq = lane >> 4;
  const int srow = wv * 8 + (lane >> 3);              // staged row (+ i*32)
  const int scol = ((lane & 7) ^ (lane >> 3)) * 8;    // pre-swizzled src col
  const int rsw = fr & 7;                             // read-side XOR
  for (int kt = kt0; kt < kt1; ++kt) {
    const int k0 = kt << 6;
#pragma unroll
    for (int i = 0; i < 4; ++i) {
      const int r = srow + i * 32;
      const int ldsoff = (i * 256 + wv * 64) * 8;     // elems; wave-uniform base
      gload16(A + (size_t)(m0 + r) * lda + (k0 + scol), As + ldsoff);
      gload16(Bt + (size_t)(n0 + r) * ldb + (k0 + scol), Bs + ldsoff);
    }
    __syncthreads();
#pragma unroll
    for (int h = 0; h < 2; ++h) {
      short8 av[4], bv[4];
      const int coff = ((h * 4 + fq) ^ rsw) * 8;
#pragma unroll
      for (int m = 0; m < 4; ++m)
        av[m] = *(const short8*)(As + (wr * 64 + m * 16 + fr) * 64 + coff);
#pragma unroll
      for (int n = 0; n < 4; ++n)
        bv[n] = *(const short8*)(Bs + (wc * 64 + n * 16 + fr) * 64 + coff);
#pragma unroll
      for (int m = 0; m < 4; ++m)
#pragma unroll
        for (int n = 0; n < 4; ++n)
          acc[m][n] = __builtin_amdgcn_mfma_f32_16x16x32_bf16(av[m], bv[n], acc[m][n], 0, 0, 0);
    }
    __syncthreads();
  }
}

#define GEMM_PROLOG                                        \
  __shared__ alignas(16) u16 As[8192];                     \
  __shared__ alignas(16) u16 Bs[8192];                     \
  const int tid = threadIdx.x;                             \
  const int lane = tid & 63, wv = tid >> 6;                \
  const int wr = wv >> 1, wc = wv & 1;                     \
  const int fr = lane & 15, fq = lane >> 4;                \
  const f32x4 fzero = {0.f, 0.f, 0.f, 0.f};                \
  f32x4 acc[4][4];                                         \
  for (int m = 0; m < 4; ++m)                              \
    for (int n = 0; n < 4; ++n) acc[m][n] = fzero;

// ---------------- fused prep kernel (R13 bodies, one launch) ----------------
// bx < 8192: X fp32->bf16; costab/sintab[t*512+fi] (idx<1M); dpow (idx<2080).
// bx >= 8192: the 7 transposes; z=(bx-8192)>>8, rem=(bx-8192)&255,
//             c0=(rem&15)*64, r0=(rem>>4)*64  (identical body to R13).
__global__ __launch_bounds__(256) void k_prep7(
    const float* __restrict__ src, u16* __restrict__ dst,
    float* __restrict__ costab, float* __restrict__ sintab,
    float* __restrict__ dpow,
    const float* __restrict__ WQ, const float* __restrict__ WK,
    const float* __restrict__ WV, const float* __restrict__ Sn,
    u16* __restrict__ Wt, u16* __restrict__ VhatT)
{
  __shared__ float tile[64][65];
  const int tid = threadIdx.x;
  const int bx = blockIdx.x;
  if (bx < 8192) {
    const int idx = bx * 256 + tid;                 // 2M threads
    const float4 v = *(const float4*)(src + (size_t)idx * 4);
    ushort4 o;
    o.x = f2bf(v.x); o.y = f2bf(v.y); o.z = f2bf(v.z); o.w = f2bf(v.w);
    *(ushort4*)(dst + (size_t)idx * 4) = o;
    if (idx < 2048 * 512) {
      const int t = idx >> 9, fi = idx & 511;
      const float invf = expf(-0.017988946039015984f * (float)fi); // 10000^(-fi/512)
      const float ang = (float)t * invf;
      costab[idx] = cosf(ang);
      sintab[idx] = sinf(ang);
    }
    if (idx < 2080) dpow[idx] = exp2f(-GLOG * (float)idx);
  } else {
    const int bb2 = bx - 8192;          // 0..1791
    const int z = bb2 >> 8;             // 0..6
    const int rem = bb2 & 255;
    const int c0 = (rem & 15) * 64, r0 = (rem >> 4) * 64;
    const float* tsrc;
    u16* tdst;
    int ldd;
    if (z == 0)      { tsrc = WQ; tdst = Wt;           ldd = 1024; }
    else if (z == 1) { tsrc = WK; tdst = Wt + 1048576; ldd = 1024; }
    else if (z == 2) { tsrc = WV; tdst = Wt + 2097152; ldd = 1024; }
    else {
      tsrc = Sn + (size_t)(z - 3) * RI_B;
      tdst = VhatT + (size_t)(z - 3) * VHT_B + 2048;
      ldd = 3072;
    }
    const int tr = tid >> 4;
    const int tc = (tid & 15) * 4;
#pragma unroll
    for (int k = 0; k < 4; ++k) {
      const float4 v = *(const float4*)(tsrc + (size_t)(r0 + tr + 16 * k) * 1024 + c0 + tc);
      tile[tr + 16 * k][tc + 0] = v.x;
      tile[tr + 16 * k][tc + 1] = v.y;
      tile[tr + 16 * k][tc + 2] = v.z;
      tile[tr + 16 * k][tc + 3] = v.w;
    }
    __syncthreads();
#pragma unroll
    for (int k = 0; k < 4; ++k) {
      const int n = tr + 16 * k;
      ushort4 o;
      o.x = f2bf(tile[tc + 0][n]);
      o.y = f2bf(tile[tc + 1][n]);
      o.z = f2bf(tile[tc + 2][n]);
      o.w = f2bf(tile[tc + 3][n]);
      *(ushort4*)(tdst + (size_t)(c0 + n) * ldd + r0 + tc) = o;
    }
  }
}

// ---------------- GEMM kernels (R13 verbatim) ----------------

// C = Xb(8192x1024) @ Wt^T(3072x1024); R1-shape rope epilogue (shared rope
// path, n-outer/m-inner, scalar table loads). Stores: Qe (Ahat cols 2048+),
// Kd (row-major decayed scalar), Ktd (col-major decayed vec), VhatT (vec).
__global__ __launch_bounds__(256, 4) void k_gemm_qkv(
    const u16* __restrict__ Xb, const u16* __restrict__ Wt,
    u16* __restrict__ Kd, u16* __restrict__ Ktd,
    u16* __restrict__ VhatT, u16* __restrict__ Ahat,
    const float* __restrict__ costab, const float* __restrict__ sintab,
    const float* __restrict__ dpow)
{
  GEMM_PROLOG;
  const int n0 = blockIdx.x * 128, m0 = blockIdx.y * 128;
  gemm_kloop(Xb, CC, Wt, CC, m0, n0, 0, 16, As, Bs, acc, lane, wv, wr, wc);

  const int bb = m0 >> 11;
  const int tb0 = m0 & 2047;

#pragma unroll
  for (int n = 0; n < 4; ++n) {
    const int col = n0 + wc * 64 + n * 16 + fr;
#pragma unroll
    for (int m = 0; m < 4; ++m) {
      const int tl = tb0 + wr * 64 + m * 16 + fq * 4;
      f32x4 v = acc[m][n];
      if (col < 2048) {
        const int c = col & 1023;
        const int fi = c >> 1;
        const float sg = (col & 1) ? 1.0f : -1.0f;
        float y[4];
#pragma unroll
        for (int j = 0; j < 4; ++j) {
          const float other = __shfl_xor(v[j], 1);
          const float cs = costab[(size_t)(tl + j) * 512 + fi];
          const float sn = sintab[(size_t)(tl + j) * 512 + fi];
          y[j] = v[j] * cs + sg * other * sn;
        }
        if (col < 1024) {
          // Qe = rope(Q) * gamma^(t+1), scalar coalesced into Ahat
#pragma unroll
          for (int j = 0; j < 4; ++j)
            Ahat[bb * AHAT_B + (size_t)(tl + j) * NQKV + 2048 + c] =
                f2bf(y[j] * dpow[tl + j + 1]);
        } else {
          // K * gamma^(2047-t): pack once -> Ktd vec + Kd scalar
          ushort4 pk;
          u16* pkp = (u16*)&pk;
#pragma unroll
          for (int j = 0; j < 4; ++j)
            pkp[j] = f2bf(y[j] * dpow[2047 - tl - j]);
          *(ushort4*)(Ktd + bb * KTD_B + (size_t)c * TT + tl) = pk;
#pragma unroll
          for (int j = 0; j < 4; ++j)
            Kd[bb * KTD_B + (size_t)(tl + j) * CC + c] = pkp[j];
        }
      } else {
        const int o = col - 2048;
        ushort4 pk;
        pk.x = f2bf(v[0]); pk.y = f2bf(v[1]); pk.z = f2bf(v[2]); pk.w = f2bf(v[3]);
        *(ushort4*)(VhatT + bb * VHT_B + (size_t)o * NQKV + tl) = pk;
      }
    }
  }
}

// Fused independent mid-stage GEMMs (both consume only qkv outputs):
//  x < 64:  R_i = Ktd @ V^T + gamma^T*S_n (32 K-tiles each — HEAVY, first)
//  x >= 64: A[t][s] = (Qe Kd^T)*gamma^-2048, masked s<=t (16 K-tiles each)
__global__ __launch_bounds__(256, 4) void k_gemm_ari(
    const u16* __restrict__ Ahat_ro, const u16* __restrict__ Kd,
    u16* __restrict__ Ahat,
    const u16* __restrict__ Ktd, const u16* __restrict__ VhatT,
    const float* __restrict__ Sn, float* __restrict__ out1,
    const float* __restrict__ dpow)
{
  GEMM_PROLOG;
  const int b = blockIdx.z;
  if (blockIdx.x < 64) {
    const int lin = blockIdx.x;          // 0..63
    const int n0 = (lin & 7) * 128;
    const int m0 = (lin >> 3) * 128;
    gemm_kloop(Ktd + b * KTD_B, TT, VhatT + b * VHT_B, NQKV,
               m0, n0, 0, 32, As, Bs, acc, lane, wv, wr, wc);
    const float gT = dpow[2048];
    const float* Sb = Sn + b * RI_B;
    float* Rb = out1 + b * RI_B;
#pragma unroll
    for (int m = 0; m < 4; ++m) {
      const int c = m0 + wr * 64 + m * 16 + fq * 4 + (fr & 3);
#pragma unroll
      for (int n = 0; n < 4; ++n) {
        const int o0 = n0 + wc * 64 + n * 16 + (fr >> 2) * 4;
        f32x4 v = acc[m][n];
        xpose4(v, lane);
        const float4 s4 = *(const float4*)(Sb + (size_t)c * CC + o0);
        v[0] += gT * s4.x; v[1] += gT * s4.y;
        v[2] += gT * s4.z; v[3] += gT * s4.w;
        *(f32x4*)(Rb + (size_t)c * CC + o0) = v;
      }
    }
  } else {
    const int lin = blockIdx.x - 64;     // 0..135
    int mi = 0;
    while ((mi + 1) * (mi + 2) / 2 <= lin) ++mi;   // largest mi: T(mi) <= lin
    const int ni = lin - mi * (mi + 1) / 2;        // 0 <= ni <= mi
    const int m0 = mi * 128, n0 = ni * 128;
    gemm_kloop(Ahat_ro + b * AHAT_B + 2048, NQKV, Kd + b * KTD_B, CC,
               m0, n0, 0, 16, As, Bs, acc, lane, wv, wr, wc);
    const float invC = exp2f(GLOG * 2048.0f);  // gamma^-2048
    u16* Ab = Ahat + b * AHAT_B;
#pragma unroll
    for (int m = 0; m < 4; ++m) {
      const int t = m0 + wr * 64 + m * 16 + fq * 4 + (fr & 3);
#pragma unroll
      for (int n = 0; n < 4; ++n) {
        const int s0 = n0 + wc * 64 + n * 16 + (fr >> 2) * 4;
        f32x4 v = acc[m][n];
        xpose4(v, lane);
        ushort4 pk;
        pk.x = f2bf(s0 + 0 <= t ? v[0] * invC : 0.f);
        pk.y = f2bf(s0 + 1 <= t ? v[1] * invC : 0.f);
        pk.z = f2bf(s0 + 2 <= t ? v[2] * invC : 0.f);
        pk.w = f2bf(s0 + 3 <= t ? v[3] * invC : 0.f);
        *(ushort4*)(Ab + (size_t)t * NQKV + s0) = pk;
      }
    }
  }
}

// out = Ahat(2048x3072) @ VhatT^T -> fp32 Obuf[t][o]
__global__ __launch_bounds__(256, 4) void k_gemm_out(
    const u16* __restrict__ Ahat, const u16* __restrict__ VhatT,
    float* __restrict__ Obuf)
{
  GEMM_PROLOG;
  const int n0 = blockIdx.x * 128;
  int mi = blockIdx.y;
  if (blockIdx.z >= 2) mi = 15 - mi;     // load-balance pairing (no math change)
  const int m0 = mi * 128;
  const int b = blockIdx.z;
  const u16* A = Ahat + b * AHAT_B;
  const u16* Bt = VhatT + b * VHT_B;
  const int kt1 = (m0 >> 6) + 2;   // only s <= t_max tiles are nonzero (BK=64)
  gemm_kloop(A, NQKV, Bt, NQKV, m0, n0, 0, kt1, As, Bs, acc, lane, wv, wr, wc);
  gemm_kloop(A, NQKV, Bt, NQKV, m0, n0, 32, 48, As, Bs, acc, lane, wv, wr, wc);
  float* Ob = Obuf + b * OBUF_B;
#pragma unroll
  for (int m = 0; m < 4; ++m) {
    const int t = m0 + wr * 64 + m * 16 + fq * 4 + (fr & 3);
    float* orow = Ob + (size_t)t * CC;
#pragma unroll
    for (int n = 0; n < 4; ++n) {
      const int c0 = n0 + wc * 64 + n * 16 + (fr >> 2) * 4;
      f32x4 v = acc[m][n];
      xpose4(v, lane);
      *(f32x4*)(orow + c0) = v;
    }
  }
}

// ---------------- GroupNorm + transposed output ----------------
// 16 t-rows per block (64 KB LDS) -> 2 blocks/CU for a memory-bound kernel.
__global__ __launch_bounds__(256) void k_gn(
    const float* __restrict__ Obuf, const float* __restrict__ gw,
    const float* __restrict__ gb, float* __restrict__ out)
{
  __shared__ float L[16][1024];
  const int bi = blockIdx.x;
  const int b = bi >> 7;
  const int t0 = (bi & 127) << 4;
  const int tid = threadIdx.x;
  const int lane = tid & 63, wv = tid >> 6;
  float wgt[16], bsv[16];
#pragma unroll
  for (int k = 0; k < 4; ++k) {
    const float4 w4 = *(const float4*)(gw + k * 256 + lane * 4);
    const float4 b4 = *(const float4*)(gb + k * 256 + lane * 4);
    wgt[k*4+0]=w4.x; wgt[k*4+1]=w4.y; wgt[k*4+2]=w4.z; wgt[k*4+3]=w4.w;
    bsv[k*4+0]=b4.x; bsv[k*4+1]=b4.y; bsv[k*4+2]=b4.z; bsv[k*4+3]=b4.w;
  }
  for (int r = wv; r < 16; r += 4) {
    const float* src = Obuf + (size_t)(b * 2048 + t0 + r) * 1024;
#pragma unroll
    for (int k = 0; k < 4; ++k) {
      const float4 x = *(const float4*)(src + k * 256 + lane * 4);
      float s = x.x + x.y + x.z + x.w;
      float q = x.x*x.x + x.y*x.y + x.z*x.z + x.w*x.w;
      s += __shfl_xor(s, 1); q += __shfl_xor(q, 1);
      s += __shfl_xor(s, 2); q += __shfl_xor(q, 2);
      s += __shfl_xor(s, 4); q += __shfl_xor(q, 4);
      const float mu = s * 0.03125f;
      const float var = q * 0.03125f - mu * mu;
      const float rs = rsqrtf(var + 1e-6f);
      float4 y;
      y.x = (x.x - mu) * rs * wgt[k*4+0] + bsv[k*4+0];
      y.y = (x.y - mu) * rs * wgt[k*4+1] + bsv[k*4+1];
      y.z = (x.z - mu) * rs * wgt[k*4+2] + bsv[k*4+2];
      y.w = (x.w - mu) * rs * wgt[k*4+3] + bsv[k*4+3];
      *(float4*)&L[r][k * 256 + lane * 4] = y;
    }
  }
  __syncthreads();
  const size_t obase = (size_t)b * 2097152 + t0;
  for (int c = tid; c < 1024; c += 256) {
    float* dst = out + obase + (size_t)c * 2048;
#pragma unroll
    for (int i = 0; i < 4; ++i) {
      float4 o4;
      o4.x = L[i*4+0][c]; o4.y = L[i*4+1][c]; o4.z = L[i*4+2][c]; o4.w = L[i*4+3][c];
      *(float4*)(dst + i * 4) = o4;
    }
  }
}

// ---------------- launch ----------------

extern "C" void kernel_launch(void* const* d_in, const int* in_sizes, int n_in,
                              void* d_out, int out_size, void* d_ws, size_t ws_size,
                              hipStream_t stream)
{
  const float* XQ = (const float*)d_in[0];
  const float* Sn = (const float*)d_in[1];
  const float* WQ = (const float*)d_in[2];
  const float* WK = (const float*)d_in[3];
  const float* WV = (const float*)d_in[4];
  const float* gw = (const float*)d_in[5];
  const float* gb = (const float*)d_in[6];
  float* out0 = (float*)d_out;
  float* out1 = out0 + 8388608;

  char* ws = (char*)d_ws;
  u16* Xb      = (u16*)(ws);                   // 16 MB (dead after qkv)
  u16* Kd      = (u16*)(ws + (16ll << 20));    // 16 MB (dead after gemm_ari)
  u16* Ktd     = (u16*)(ws + (32ll << 20));    // 16 MB
  u16* Ahat    = (u16*)(ws + (48ll << 20));    // 48 MB [t][0:2048]=A, [2048:3072]=Qe
  u16* VhatT   = (u16*)(ws + (96ll << 20));    // 24 MB [o][0:2048]=V^T, [2048:3072]=Sn^T
  u16* Wt      = (u16*)(ws + (120ll << 20));   // 6 MB
  float* costab = (float*)(ws + (126ll << 20)); // 4 MB
  float* sintab = (float*)(ws + (130ll << 20)); // 4 MB
  float* dpow   = (float*)(ws + (134ll << 20)); // ~8 KB
  float* Obuf   = (float*)(ws);                // 32 MB, aliases Xb+Kd (both dead)

  k_prep7<<<9984, 256, 0, stream>>>(XQ, Xb, costab, sintab, dpow,
                                    WQ, WK, WV, Sn, Wt, VhatT);
  k_gemm_qkv<<<dim3(24, 64), 256, 0, stream>>>(Xb, Wt, Kd, Ktd, VhatT, Ahat,
                                               costab, sintab, dpow);
  k_gemm_ari<<<dim3(200, 1, 4), 256, 0, stream>>>(Ahat, Kd, Ahat, Ktd, VhatT,
                                                  Sn, out1, dpow);
  k_gemm_out<<<dim3(8, 16, 4), 256, 0, stream>>>(Ahat, VhatT, Obuf);
  k_gn<<<512, 256, 0, stream>>>(Obuf, gw, gb, out0);
}